// Round 1
// baseline (11815.699 us; speedup 1.0000x reference)
//
#include <hip/hip_runtime.h>
#include <cstdint>
#include <cstddef>

#define TT 2048
#define VV 32000
#define EE 512
#define HH 1024

typedef __bf16 bf16x8 __attribute__((ext_vector_type(8)));
typedef float f32x4 __attribute__((ext_vector_type(4)));

static __device__ __forceinline__ unsigned short f2b(float f) {
    unsigned u = __float_as_uint(f);
    unsigned r = (u + 0x7fffu + ((u >> 16) & 1u)) >> 16;   // RNE
    return (unsigned short)r;
}

// ---------------- embedding gather -> bf16 ----------------
__global__ __launch_bounds__(128) void embed_kernel(
    const int* __restrict__ tok, const float* __restrict__ emb,
    unsigned short* __restrict__ xs_b) {
    int t = blockIdx.x;
    int e4 = threadIdx.x;                       // 128 threads * 4 floats = 512
    const float4* src = (const float4*)(emb + (size_t)tok[t] * EE);
    float4 v = src[e4];
    ushort4 o;
    o.x = f2b(v.x); o.y = f2b(v.y); o.z = f2b(v.z); o.w = f2b(v.w);
    ((ushort4*)(xs_b + (size_t)t * EE))[e4] = o;
}

// ---------------- generic f32 -> bf16 ----------------
__global__ __launch_bounds__(256) void f32_to_bf16(
    const float* __restrict__ in, unsigned short* __restrict__ out, long n4) {
    long i = (long)blockIdx.x * blockDim.x + threadIdx.x;
    long stride = (long)gridDim.x * blockDim.x;
    for (; i < n4; i += stride) {
        float4 v = ((const float4*)in)[i];
        ushort4 o;
        o.x = f2b(v.x); o.y = f2b(v.y); o.z = f2b(v.z); o.w = f2b(v.w);
        ((ushort4*)out)[i] = o;
    }
}

// ---------------- bf16 MFMA GEMM: C[M,N] = A[M,K] * B[N,K]^T + bias ----------------
// 128x128 tile, BK=64, 4 waves (2x2), each wave 64x64 via 4x4 16x16x32 MFMAs.
// LDS XOR-swizzled (T2): byte = row*128 + (kbyte ^ ((row&7)<<4))
__global__ __launch_bounds__(256) void gemm_bf16_nt(
    const unsigned short* __restrict__ A,   // [M][K] bf16 bits
    const unsigned short* __restrict__ B,   // [N][K] bf16 bits
    const float* __restrict__ bias1,        // [N] or null
    const float* __restrict__ bias2,        // [N] or null
    float* __restrict__ C,                  // [M][N]
    int K, int N) {
    __shared__ unsigned short ldsA[128 * 64];
    __shared__ unsigned short ldsB[128 * 64];
    const int tid = threadIdx.x;
    const int l = tid & 63;
    const int w = tid >> 6;
    const int wm = (w >> 1) * 64;
    const int wn = (w & 1) * 64;
    const int bm = blockIdx.y, bn = blockIdx.x;
    const size_t a_base = (size_t)bm * 128 * K;
    const size_t b_base = (size_t)bn * 128 * K;
    const int srow = tid >> 3;   // 0..31
    const int skc = tid & 7;     // 16B chunk within 128B

    f32x4 acc[4][4];
    for (int i = 0; i < 4; ++i)
        for (int j = 0; j < 4; ++j)
            acc[i][j] = (f32x4){0.f, 0.f, 0.f, 0.f};

    for (int kt = 0; kt < K; kt += 64) {
        uint4 av[4], bv[4];
#pragma unroll
        for (int i = 0; i < 4; ++i) {
            int row = srow + i * 32;
            av[i] = ((const uint4*)(A + a_base + (size_t)row * K + kt))[skc];
            bv[i] = ((const uint4*)(B + b_base + (size_t)row * K + kt))[skc];
        }
        __syncthreads();
#pragma unroll
        for (int i = 0; i < 4; ++i) {
            int row = srow + i * 32;
            int off = row * 128 + ((skc * 16) ^ ((row & 7) << 4));
            *(uint4*)((char*)ldsA + off) = av[i];
            *(uint4*)((char*)ldsB + off) = bv[i];
        }
        __syncthreads();
#pragma unroll
        for (int ks = 0; ks < 2; ++ks) {
            bf16x8 af[4], bfr[4];
            int kb = ks * 64 + (l >> 4) * 16;
#pragma unroll
            for (int f = 0; f < 4; ++f) {
                int ar = wm + f * 16 + (l & 15);
                af[f] = *(const bf16x8*)((const char*)ldsA + ar * 128 + (kb ^ ((ar & 7) << 4)));
                int br = wn + f * 16 + (l & 15);
                bfr[f] = *(const bf16x8*)((const char*)ldsB + br * 128 + (kb ^ ((br & 7) << 4)));
            }
#pragma unroll
            for (int fm = 0; fm < 4; ++fm)
#pragma unroll
                for (int fn = 0; fn < 4; ++fn)
                    acc[fm][fn] = __builtin_amdgcn_mfma_f32_16x16x32_bf16(
                        af[fm], bfr[fn], acc[fm][fn], 0, 0, 0);
        }
    }
    // epilogue: C/D layout col = l&15, row = (l>>4)*4 + r  [m89/m91 verified]
    const int r0 = (l >> 4) * 4, cn = (l & 15);
#pragma unroll
    for (int fm = 0; fm < 4; ++fm)
#pragma unroll
        for (int fn = 0; fn < 4; ++fn) {
            int col = bn * 128 + wn + fn * 16 + cn;
            float bb = (bias1 ? bias1[col] : 0.f) + (bias2 ? bias2[col] : 0.f);
#pragma unroll
            for (int r = 0; r < 4; ++r) {
                int rowg = bm * 128 + wm + fm * 16 + r0 + r;
                C[(size_t)rowg * N + col] = acc[fm][fn][r] + bb;
            }
        }
}

// ---------------- persistent LSTM recurrence ----------------
// 256 blocks x 256 threads. Block b owns hidden units j0=4b..4b+3 (16 W_hh rows).
// Weights fp32 in registers: wave g (=gate) lane cg holds W[g*H+j0+u][cg+64k], k=0..15.
// Cross-block per-step sync: tagged[parity][j] = {tag=t+1 (hi32), h bits (lo32)} u64.
__global__ __launch_bounds__(256) void lstm_layer(
    const float* __restrict__ Whh,              // [4H][H]
    const float* __restrict__ pre,              // [T][4H] (includes biases)
    float* __restrict__ ys,                     // [T][H]
    unsigned long long* __restrict__ tagged,    // [2][H]
    float* __restrict__ h_final,                // [H]
    float* __restrict__ c_final) {              // [H]
    const int b = blockIdx.x;
    const int tid = threadIdx.x;
    const int gate = tid >> 6;   // wave id == gate (i,f,g,o)
    const int lane = tid & 63;
    const int j0 = b * 4;

    float wreg[4][16];
#pragma unroll
    for (int u = 0; u < 4; ++u) {
        const float* row = Whh + (size_t)(gate * HH + j0 + u) * HH;
#pragma unroll
        for (int k = 0; k < 16; ++k) wreg[u][k] = row[lane + 64 * k];
    }

    __shared__ float h_lds[HH];
    __shared__ float gdot[4][4];

    float c_reg = 0.f;   // valid in tid<4

    for (int t = 0; t < TT; ++t) {
        // prefetch px early (independent of h_{t-1})
        float px0 = 0.f, px1 = 0.f, px2 = 0.f, px3 = 0.f;
        if (tid < 4) {
            const float* p = pre + (size_t)t * (4 * HH) + (j0 + tid);
            px0 = p[0 * HH]; px1 = p[1 * HH]; px2 = p[2 * HH]; px3 = p[3 * HH];
        }
        if (t > 0) {
            const unsigned long long* src = tagged + (size_t)(t & 1) * HH;
            const unsigned long long want = (unsigned long long)t << 32;
            unsigned long long v[4] = {0ull, 0ull, 0ull, 0ull};
            bool ok;
            do {
                ok = true;
#pragma unroll
                for (int q = 0; q < 4; ++q) {
                    if ((v[q] & 0xffffffff00000000ull) != want) {
                        v[q] = __hip_atomic_load(src + tid + 256 * q,
                                                 __ATOMIC_RELAXED, __HIP_MEMORY_SCOPE_AGENT);
                        if ((v[q] & 0xffffffff00000000ull) != want) ok = false;
                    }
                }
                if (!ok) __builtin_amdgcn_s_sleep(1);
            } while (!ok);
#pragma unroll
            for (int q = 0; q < 4; ++q)
                h_lds[tid + 256 * q] = __uint_as_float((unsigned)(v[q] & 0xffffffffu));
            __syncthreads();

            float dot0 = 0.f, dot1 = 0.f, dot2 = 0.f, dot3 = 0.f;
#pragma unroll
            for (int k = 0; k < 16; ++k) {
                float hv = h_lds[lane + 64 * k];
                dot0 += wreg[0][k] * hv;
                dot1 += wreg[1][k] * hv;
                dot2 += wreg[2][k] * hv;
                dot3 += wreg[3][k] * hv;
            }
#pragma unroll
            for (int off = 32; off; off >>= 1) {
                dot0 += __shfl_xor(dot0, off);
                dot1 += __shfl_xor(dot1, off);
                dot2 += __shfl_xor(dot2, off);
                dot3 += __shfl_xor(dot3, off);
            }
            if (lane == 0) {
                gdot[gate][0] = dot0; gdot[gate][1] = dot1;
                gdot[gate][2] = dot2; gdot[gate][3] = dot3;
            }
            __syncthreads();
        } else {
            if (tid < 16) gdot[tid >> 2][tid & 3] = 0.f;
            __syncthreads();
        }

        if (tid < 4) {
            const int u = tid, j = j0 + u;
            float gi = px0 + gdot[0][u];
            float gf = px1 + gdot[1][u];
            float gg = px2 + gdot[2][u];
            float go = px3 + gdot[3][u];
            float i_ = 1.f / (1.f + expf(-gi));
            float f_ = 1.f / (1.f + expf(-gf));
            float g_ = tanhf(gg);
            float o_ = 1.f / (1.f + expf(-go));
            c_reg = f_ * c_reg + i_ * g_;
            float h_ = o_ * tanhf(c_reg);
            ys[(size_t)t * HH + j] = h_;
            unsigned long long pack =
                ((unsigned long long)(t + 1) << 32) | (unsigned long long)__float_as_uint(h_);
            __hip_atomic_store(tagged + (size_t)((t + 1) & 1) * HH + j, pack,
                               __ATOMIC_RELAXED, __HIP_MEMORY_SCOPE_AGENT);
            if (t == TT - 1) { h_final[j] = h_; c_final[j] = c_reg; }
        }
        __syncthreads();   // protect h_lds/gdot reuse next step
    }
}

// ---------------- row softmax over V=32000, in place ----------------
__global__ __launch_bounds__(256) void softmax_kernel(float* __restrict__ data) {
    const int row = blockIdx.x;
    const int tid = threadIdx.x;
    float* p = data + (size_t)row * VV;
    float m = -1e30f, s = 0.f;
    for (int i = tid * 4; i < VV; i += 1024) {
        float4 v = *(const float4*)(p + i);
        float x[4] = {v.x, v.y, v.z, v.w};
#pragma unroll
        for (int q = 0; q < 4; ++q) {
            float xv = x[q];
            if (xv > m) { s = s * __expf(m - xv) + 1.f; m = xv; }
            else s += __expf(xv - m);
        }
    }
#pragma unroll
    for (int off = 32; off; off >>= 1) {
        float mo = __shfl_xor(m, off);
        float so = __shfl_xor(s, off);
        float mn = fmaxf(m, mo);
        s = s * __expf(m - mn) + so * __expf(mo - mn);
        m = mn;
    }
    __shared__ float sm[4], ss[4];
    int wv = tid >> 6;
    if ((tid & 63) == 0) { sm[wv] = m; ss[wv] = s; }
    __syncthreads();
    float M = fmaxf(fmaxf(sm[0], sm[1]), fmaxf(sm[2], sm[3]));
    float S = ss[0] * __expf(sm[0] - M) + ss[1] * __expf(sm[1] - M) +
              ss[2] * __expf(sm[2] - M) + ss[3] * __expf(sm[3] - M);
    float inv = 1.f / S;
    for (int i = tid * 4; i < VV; i += 1024) {
        float4 v = *(const float4*)(p + i);
        v.x = __expf(v.x - M) * inv;
        v.y = __expf(v.y - M) * inv;
        v.z = __expf(v.z - M) * inv;
        v.w = __expf(v.w - M) * inv;
        *(float4*)(p + i) = v;
    }
}

extern "C" void kernel_launch(void* const* d_in, const int* in_sizes, int n_in,
                              void* d_out, int out_size, void* d_ws, size_t ws_size,
                              hipStream_t stream) {
    const int*   inputs = (const int*)d_in[0];
    const float* emb    = (const float*)d_in[1];
    const float* w_ih0  = (const float*)d_in[2];
    const float* w_hh0  = (const float*)d_in[3];
    const float* b_ih0  = (const float*)d_in[4];
    const float* b_hh0  = (const float*)d_in[5];
    const float* w_ih1  = (const float*)d_in[6];
    const float* w_hh1  = (const float*)d_in[7];
    const float* b_ih1  = (const float*)d_in[8];
    const float* b_hh1  = (const float*)d_in[9];
    const float* w_out  = (const float*)d_in[10];
    const float* b_out  = (const float*)d_in[11];
    float* out = (float*)d_out;

    char* ws = (char*)d_ws;
    size_t off = 0;
    auto alloc = [&](size_t bytes) -> void* {
        void* p = ws + off;
        off += (bytes + 255) & ~(size_t)255;
        return p;
    };
    float* pre           = (float*)alloc((size_t)TT * 4 * HH * 4);
    float* ys0           = (float*)alloc((size_t)TT * HH * 4);
    float* ys1           = (float*)alloc((size_t)TT * HH * 4);
    unsigned short* xsb  = (unsigned short*)alloc((size_t)TT * EE * 2);
    unsigned short* w0b  = (unsigned short*)alloc((size_t)4 * HH * EE * 2);
    unsigned short* w1b  = (unsigned short*)alloc((size_t)4 * HH * HH * 2);
    unsigned short* wob  = (unsigned short*)alloc((size_t)VV * HH * 2);
    unsigned short* y0b  = (unsigned short*)alloc((size_t)TT * HH * 2);
    unsigned short* y1b  = (unsigned short*)alloc((size_t)TT * HH * 2);
    unsigned long long* tag0 = (unsigned long long*)alloc(2 * HH * 8);
    unsigned long long* tag1 = (unsigned long long*)alloc(2 * HH * 8);
    if (off > ws_size) return;   // workspace insufficient -> visible failure, no corruption

    (void)hipMemsetAsync(tag0, 0, 2 * HH * 8, stream);
    (void)hipMemsetAsync(tag1, 0, 2 * HH * 8, stream);

    embed_kernel<<<TT, 128, 0, stream>>>(inputs, emb, xsb);
    f32_to_bf16<<<1024, 256, 0, stream>>>(w_ih0, w0b, (long)4 * HH * EE / 4);
    f32_to_bf16<<<1024, 256, 0, stream>>>(w_ih1, w1b, (long)4 * HH * HH / 4);
    f32_to_bf16<<<2048, 256, 0, stream>>>(w_out, wob, (long)VV * HH / 4);

    // pre0 = xs @ w_ih0^T + b_ih0 + b_hh0
    gemm_bf16_nt<<<dim3(4 * HH / 128, TT / 128), 256, 0, stream>>>(
        xsb, w0b, b_ih0, b_hh0, pre, EE, 4 * HH);
    lstm_layer<<<256, 256, 0, stream>>>(w_hh0, pre, ys0, tag0,
                                        out + (size_t)TT * VV,
                                        out + (size_t)TT * VV + 2 * HH);
    f32_to_bf16<<<1024, 256, 0, stream>>>(ys0, y0b, (long)TT * HH / 4);

    // pre1 = ys0 @ w_ih1^T + b_ih1 + b_hh1
    gemm_bf16_nt<<<dim3(4 * HH / 128, TT / 128), 256, 0, stream>>>(
        y0b, w1b, b_ih1, b_hh1, pre, HH, 4 * HH);
    lstm_layer<<<256, 256, 0, stream>>>(w_hh1, pre, ys1, tag1,
                                        out + (size_t)TT * VV + HH,
                                        out + (size_t)TT * VV + 3 * HH);
    f32_to_bf16<<<1024, 256, 0, stream>>>(ys1, y1b, (long)TT * HH / 4);

    // logits = ys1 @ w_out^T + b_out  (into d_out, softmax in place after)
    gemm_bf16_nt<<<dim3(VV / 128, TT / 128), 256, 0, stream>>>(
        y1b, wob, b_out, nullptr, out, HH, VV);
    softmax_kernel<<<TT, 256, 0, stream>>>(out);
}

// Round 2
// 8391.895 us; speedup vs baseline: 1.4080x; 1.4080x over previous
//
#include <hip/hip_runtime.h>
#include <cstdint>
#include <cstddef>

#define TT 2048
#define VV 32000
#define EE 512
#define HH 1024
#define LBLK 128   // blocks per layer in lstm_fused

typedef __bf16 bf16x8 __attribute__((ext_vector_type(8)));
typedef float f32x4 __attribute__((ext_vector_type(4)));

static __device__ __forceinline__ unsigned short f2b(float f) {
    unsigned u = __float_as_uint(f);
    unsigned r = (u + 0x7fffu + ((u >> 16) & 1u)) >> 16;   // RNE
    return (unsigned short)r;
}

// ---------------- embedding gather -> bf16 ----------------
__global__ __launch_bounds__(128) void embed_kernel(
    const int* __restrict__ tok, const float* __restrict__ emb,
    unsigned short* __restrict__ xs_b) {
    int t = blockIdx.x;
    int e4 = threadIdx.x;
    const float4* src = (const float4*)(emb + (size_t)tok[t] * EE);
    float4 v = src[e4];
    ushort4 o;
    o.x = f2b(v.x); o.y = f2b(v.y); o.z = f2b(v.z); o.w = f2b(v.w);
    ((ushort4*)(xs_b + (size_t)t * EE))[e4] = o;
}

// ---------------- generic f32 -> bf16 ----------------
__global__ __launch_bounds__(256) void f32_to_bf16(
    const float* __restrict__ in, unsigned short* __restrict__ out, long n4) {
    long i = (long)blockIdx.x * blockDim.x + threadIdx.x;
    long stride = (long)gridDim.x * blockDim.x;
    for (; i < n4; i += stride) {
        float4 v = ((const float4*)in)[i];
        ushort4 o;
        o.x = f2b(v.x); o.y = f2b(v.y); o.z = f2b(v.z); o.w = f2b(v.w);
        ((ushort4*)out)[i] = o;
    }
}

// ---------------- bf16 MFMA GEMM: C[M,N] = A[M,K] * B[N,K]^T + bias ----------------
__global__ __launch_bounds__(256) void gemm_bf16_nt(
    const unsigned short* __restrict__ A,   // [M][K] bf16 bits
    const unsigned short* __restrict__ B,   // [N][K] bf16 bits
    const float* __restrict__ bias1,        // [N] or null
    const float* __restrict__ bias2,        // [N] or null
    float* __restrict__ C,                  // [M][N]
    int K, int N) {
    __shared__ unsigned short ldsA[128 * 64];
    __shared__ unsigned short ldsB[128 * 64];
    const int tid = threadIdx.x;
    const int l = tid & 63;
    const int w = tid >> 6;
    const int wm = (w >> 1) * 64;
    const int wn = (w & 1) * 64;
    const int bm = blockIdx.y, bn = blockIdx.x;
    const size_t a_base = (size_t)bm * 128 * K;
    const size_t b_base = (size_t)bn * 128 * K;
    const int srow = tid >> 3;
    const int skc = tid & 7;

    f32x4 acc[4][4];
    for (int i = 0; i < 4; ++i)
        for (int j = 0; j < 4; ++j)
            acc[i][j] = (f32x4){0.f, 0.f, 0.f, 0.f};

    for (int kt = 0; kt < K; kt += 64) {
        uint4 av[4], bv[4];
#pragma unroll
        for (int i = 0; i < 4; ++i) {
            int row = srow + i * 32;
            av[i] = ((const uint4*)(A + a_base + (size_t)row * K + kt))[skc];
            bv[i] = ((const uint4*)(B + b_base + (size_t)row * K + kt))[skc];
        }
        __syncthreads();
#pragma unroll
        for (int i = 0; i < 4; ++i) {
            int row = srow + i * 32;
            int off = row * 128 + ((skc * 16) ^ ((row & 7) << 4));
            *(uint4*)((char*)ldsA + off) = av[i];
            *(uint4*)((char*)ldsB + off) = bv[i];
        }
        __syncthreads();
#pragma unroll
        for (int ks = 0; ks < 2; ++ks) {
            bf16x8 af[4], bfr[4];
            int kb = ks * 64 + (l >> 4) * 16;
#pragma unroll
            for (int f = 0; f < 4; ++f) {
                int ar = wm + f * 16 + (l & 15);
                af[f] = *(const bf16x8*)((const char*)ldsA + ar * 128 + (kb ^ ((ar & 7) << 4)));
                int br = wn + f * 16 + (l & 15);
                bfr[f] = *(const bf16x8*)((const char*)ldsB + br * 128 + (kb ^ ((br & 7) << 4)));
            }
#pragma unroll
            for (int fm = 0; fm < 4; ++fm)
#pragma unroll
                for (int fn = 0; fn < 4; ++fn)
                    acc[fm][fn] = __builtin_amdgcn_mfma_f32_16x16x32_bf16(
                        af[fm], bfr[fn], acc[fm][fn], 0, 0, 0);
        }
    }
    const int r0 = (l >> 4) * 4, cn = (l & 15);
#pragma unroll
    for (int fm = 0; fm < 4; ++fm)
#pragma unroll
        for (int fn = 0; fn < 4; ++fn) {
            int col = bn * 128 + wn + fn * 16 + cn;
            float bb = (bias1 ? bias1[col] : 0.f) + (bias2 ? bias2[col] : 0.f);
#pragma unroll
            for (int r = 0; r < 4; ++r) {
                int rowg = bm * 128 + wm + fm * 16 + r0 + r;
                C[(size_t)rowg * N + col] = acc[fm][fn][r] + bb;
            }
        }
}

// ---------------- fused 2-layer pipelined LSTM recurrence ----------------
// 256 blocks x 512 threads. Blocks 0..127: layer 0; 128..255: layer 1 (runs
// 1 step behind, consuming h0 via full-history tagged hist0[T][H]).
// Each block owns 8 hidden units; wave u owns unit j = j0+u; W rows fp32 in regs.
// Per-step sync: tagged u64 {tag (hi32), f32 h bits (lo32)}, agent-scope relaxed.
__global__ __launch_bounds__(512, 2) void lstm_fused(
    const float* __restrict__ Whh0,           // [4H][H]
    const float* __restrict__ pre0,           // [T][4H] (x-proj + biases, layer 0)
    const float* __restrict__ Wih1,           // [4H][H]
    const float* __restrict__ Whh1,           // [4H][H]
    const float* __restrict__ bih1,           // [4H]
    const float* __restrict__ bhh1,           // [4H]
    unsigned long long* __restrict__ hist0,   // [T][H] tagged h0 history
    unsigned long long* __restrict__ tag1,    // [2][H] tagged h1 double buffer
    unsigned short* __restrict__ y1b,         // [T][H] bf16 layer-1 output
    float* __restrict__ hfb,                  // out + T*V      (h stack [2][H])
    float* __restrict__ cfb) {                // out + T*V + 2H (c stack [2][H])
    const int tid  = threadIdx.x;
    const int wv   = tid >> 6;
    const int lane = tid & 63;
    const int e0   = tid * 2;            // staged entry pair

    __shared__ float hA[2][HH];
    __shared__ float hB[2][HH];

    if (blockIdx.x < LBLK) {
        // ================= layer 0 =================
        const int j = blockIdx.x * 8 + wv;
        float w[4][16];
#pragma unroll
        for (int g = 0; g < 4; ++g)
#pragma unroll
            for (int k = 0; k < 16; ++k)
                w[g][k] = Whh0[(size_t)(g * HH + j) * HH + lane + 64 * k];

        float c = 0.f;
        for (int t = 0; t < TT; ++t) {
            float px0 = pre0[(size_t)t * 4 * HH + 0 * HH + j];
            float px1 = pre0[(size_t)t * 4 * HH + 1 * HH + j];
            float px2 = pre0[(size_t)t * 4 * HH + 2 * HH + j];
            float px3 = pre0[(size_t)t * 4 * HH + 3 * HH + j];
            const int par = t & 1;
            if (t > 0) {
                const unsigned long long* src = hist0 + (size_t)(t - 1) * HH;
                const unsigned want = (unsigned)t;
                unsigned long long v0 = 0, v1 = 0;
                bool r0 = false, r1 = false;
                while (true) {
                    if (!r0) { v0 = __hip_atomic_load(src + e0,     __ATOMIC_RELAXED, __HIP_MEMORY_SCOPE_AGENT); r0 = (unsigned)(v0 >> 32) == want; }
                    if (!r1) { v1 = __hip_atomic_load(src + e0 + 1, __ATOMIC_RELAXED, __HIP_MEMORY_SCOPE_AGENT); r1 = (unsigned)(v1 >> 32) == want; }
                    if (r0 & r1) break;
                    __builtin_amdgcn_s_sleep(1);
                }
                hA[par][e0]     = __uint_as_float((unsigned)v0);
                hA[par][e0 + 1] = __uint_as_float((unsigned)v1);
            } else {
                hA[par][e0] = 0.f; hA[par][e0 + 1] = 0.f;
            }
            __syncthreads();
            float d0 = 0.f, d1 = 0.f, d2 = 0.f, d3 = 0.f;
#pragma unroll
            for (int k = 0; k < 16; ++k) {
                float hv = hA[par][lane + 64 * k];
                d0 += w[0][k] * hv; d1 += w[1][k] * hv;
                d2 += w[2][k] * hv; d3 += w[3][k] * hv;
            }
#pragma unroll
            for (int off = 32; off; off >>= 1) {
                d0 += __shfl_xor(d0, off); d1 += __shfl_xor(d1, off);
                d2 += __shfl_xor(d2, off); d3 += __shfl_xor(d3, off);
            }
            float gi = px0 + d0, gf = px1 + d1, gg = px2 + d2, go = px3 + d3;
            float i_ = 1.f / (1.f + __expf(-gi));
            float f_ = 1.f / (1.f + __expf(-gf));
            float eg = __expf(-2.f * gg); float g_ = (1.f - eg) / (1.f + eg);
            float o_ = 1.f / (1.f + __expf(-go));
            c = f_ * c + i_ * g_;
            float ec = __expf(-2.f * c); float tc = (1.f - ec) / (1.f + ec);
            float h = o_ * tc;
            if (lane == 0) {
                __hip_atomic_store(hist0 + (size_t)t * HH + j,
                    ((unsigned long long)(unsigned)(t + 1) << 32) |
                    (unsigned long long)__float_as_uint(h),
                    __ATOMIC_RELAXED, __HIP_MEMORY_SCOPE_AGENT);
                if (t == TT - 1) { hfb[j] = h; cfb[j] = c; }
            }
        }
    } else {
        // ================= layer 1 (pipelined, 1 step behind) =================
        const int j = (blockIdx.x - LBLK) * 8 + wv;
        float wi[4][16], wh[4][16], bs[4];
#pragma unroll
        for (int g = 0; g < 4; ++g) {
#pragma unroll
            for (int k = 0; k < 16; ++k) {
                wi[g][k] = Wih1[(size_t)(g * HH + j) * HH + lane + 64 * k];
                wh[g][k] = Whh1[(size_t)(g * HH + j) * HH + lane + 64 * k];
            }
            bs[g] = bih1[g * HH + j] + bhh1[g * HH + j];
        }

        float c = 0.f;
        for (int t = 0; t < TT; ++t) {
            const int par = t & 1;
            // ---- stage h0_t (layer-0 output, tag t+1) ----
            {
                const unsigned long long* src = hist0 + (size_t)t * HH;
                const unsigned want = (unsigned)(t + 1);
                unsigned long long v0 = 0, v1 = 0;
                bool r0 = false, r1 = false;
                while (true) {
                    if (!r0) { v0 = __hip_atomic_load(src + e0,     __ATOMIC_RELAXED, __HIP_MEMORY_SCOPE_AGENT); r0 = (unsigned)(v0 >> 32) == want; }
                    if (!r1) { v1 = __hip_atomic_load(src + e0 + 1, __ATOMIC_RELAXED, __HIP_MEMORY_SCOPE_AGENT); r1 = (unsigned)(v1 >> 32) == want; }
                    if (r0 & r1) break;
                    __builtin_amdgcn_s_sleep(1);
                }
                hA[par][e0]     = __uint_as_float((unsigned)v0);
                hA[par][e0 + 1] = __uint_as_float((unsigned)v1);
            }
            __syncthreads();
            // ---- input-projection half-dot (independent of h1_{t-1}) ----
            float d0 = 0.f, d1 = 0.f, d2 = 0.f, d3 = 0.f;
#pragma unroll
            for (int k = 0; k < 16; ++k) {
                float hv = hA[par][lane + 64 * k];
                d0 += wi[0][k] * hv; d1 += wi[1][k] * hv;
                d2 += wi[2][k] * hv; d3 += wi[3][k] * hv;
            }
            // ---- stage h1_{t-1} (tag t, slot t&1) ----
            if (t > 0) {
                const unsigned long long* src = tag1 + (size_t)par * HH;
                const unsigned want = (unsigned)t;
                unsigned long long v0 = 0, v1 = 0;
                bool r0 = false, r1 = false;
                while (true) {
                    if (!r0) { v0 = __hip_atomic_load(src + e0,     __ATOMIC_RELAXED, __HIP_MEMORY_SCOPE_AGENT); r0 = (unsigned)(v0 >> 32) == want; }
                    if (!r1) { v1 = __hip_atomic_load(src + e0 + 1, __ATOMIC_RELAXED, __HIP_MEMORY_SCOPE_AGENT); r1 = (unsigned)(v1 >> 32) == want; }
                    if (r0 & r1) break;
                    __builtin_amdgcn_s_sleep(1);
                }
                hB[par][e0]     = __uint_as_float((unsigned)v0);
                hB[par][e0 + 1] = __uint_as_float((unsigned)v1);
            } else {
                hB[par][e0] = 0.f; hB[par][e0 + 1] = 0.f;
            }
            __syncthreads();
#pragma unroll
            for (int k = 0; k < 16; ++k) {
                float hv = hB[par][lane + 64 * k];
                d0 += wh[0][k] * hv; d1 += wh[1][k] * hv;
                d2 += wh[2][k] * hv; d3 += wh[3][k] * hv;
            }
#pragma unroll
            for (int off = 32; off; off >>= 1) {
                d0 += __shfl_xor(d0, off); d1 += __shfl_xor(d1, off);
                d2 += __shfl_xor(d2, off); d3 += __shfl_xor(d3, off);
            }
            float gi = bs[0] + d0, gf = bs[1] + d1, gg = bs[2] + d2, go = bs[3] + d3;
            float i_ = 1.f / (1.f + __expf(-gi));
            float f_ = 1.f / (1.f + __expf(-gf));
            float eg = __expf(-2.f * gg); float g_ = (1.f - eg) / (1.f + eg);
            float o_ = 1.f / (1.f + __expf(-go));
            c = f_ * c + i_ * g_;
            float ec = __expf(-2.f * c); float tc = (1.f - ec) / (1.f + ec);
            float h = o_ * tc;
            if (lane == 0) {
                __hip_atomic_store(tag1 + (size_t)((t + 1) & 1) * HH + j,
                    ((unsigned long long)(unsigned)(t + 1) << 32) |
                    (unsigned long long)__float_as_uint(h),
                    __ATOMIC_RELAXED, __HIP_MEMORY_SCOPE_AGENT);
                y1b[(size_t)t * HH + j] = f2b(h);
                if (t == TT - 1) { hfb[HH + j] = h; cfb[HH + j] = c; }
            }
        }
    }
}

// ---------------- row softmax over V=32000, in place ----------------
__global__ __launch_bounds__(256) void softmax_kernel(float* __restrict__ data) {
    const int row = blockIdx.x;
    const int tid = threadIdx.x;
    float* p = data + (size_t)row * VV;
    float m = -1e30f, s = 0.f;
    for (int i = tid * 4; i < VV; i += 1024) {
        float4 v = *(const float4*)(p + i);
        float x[4] = {v.x, v.y, v.z, v.w};
#pragma unroll
        for (int q = 0; q < 4; ++q) {
            float xv = x[q];
            if (xv > m) { s = s * __expf(m - xv) + 1.f; m = xv; }
            else s += __expf(xv - m);
        }
    }
#pragma unroll
    for (int off = 32; off; off >>= 1) {
        float mo = __shfl_xor(m, off);
        float so = __shfl_xor(s, off);
        float mn = fmaxf(m, mo);
        s = s * __expf(m - mn) + so * __expf(mo - mn);
        m = mn;
    }
    __shared__ float sm[4], ss[4];
    int wvv = tid >> 6;
    if ((tid & 63) == 0) { sm[wvv] = m; ss[wvv] = s; }
    __syncthreads();
    float M = fmaxf(fmaxf(sm[0], sm[1]), fmaxf(sm[2], sm[3]));
    float S = ss[0] * __expf(sm[0] - M) + ss[1] * __expf(sm[1] - M) +
              ss[2] * __expf(sm[2] - M) + ss[3] * __expf(sm[3] - M);
    float inv = 1.f / S;
    for (int i = tid * 4; i < VV; i += 1024) {
        float4 v = *(const float4*)(p + i);
        v.x = __expf(v.x - M) * inv;
        v.y = __expf(v.y - M) * inv;
        v.z = __expf(v.z - M) * inv;
        v.w = __expf(v.w - M) * inv;
        *(float4*)(p + i) = v;
    }
}

extern "C" void kernel_launch(void* const* d_in, const int* in_sizes, int n_in,
                              void* d_out, int out_size, void* d_ws, size_t ws_size,
                              hipStream_t stream) {
    const int*   inputs = (const int*)d_in[0];
    const float* emb    = (const float*)d_in[1];
    const float* w_ih0  = (const float*)d_in[2];
    const float* w_hh0  = (const float*)d_in[3];
    const float* b_ih0  = (const float*)d_in[4];
    const float* b_hh0  = (const float*)d_in[5];
    const float* w_ih1  = (const float*)d_in[6];
    const float* w_hh1  = (const float*)d_in[7];
    const float* b_ih1  = (const float*)d_in[8];
    const float* b_hh1  = (const float*)d_in[9];
    const float* w_out  = (const float*)d_in[10];
    const float* b_out  = (const float*)d_in[11];
    float* out = (float*)d_out;

    char* ws = (char*)d_ws;
    size_t off = 0;
    auto alloc = [&](size_t bytes) -> void* {
        void* p = ws + off;
        off += (bytes + 255) & ~(size_t)255;
        return p;
    };
    float* pre0          = (float*)alloc((size_t)TT * 4 * HH * 4);
    unsigned short* xsb  = (unsigned short*)alloc((size_t)TT * EE * 2);
    unsigned short* w0b  = (unsigned short*)alloc((size_t)4 * HH * EE * 2);
    unsigned short* wob  = (unsigned short*)alloc((size_t)VV * HH * 2);
    unsigned short* y1b  = (unsigned short*)alloc((size_t)TT * HH * 2);
    unsigned long long* hist0 = (unsigned long long*)alloc((size_t)TT * HH * 8);
    unsigned long long* tag1  = (unsigned long long*)alloc(2 * HH * 8);
    if (off > ws_size) return;

    (void)hipMemsetAsync(hist0, 0, (size_t)TT * HH * 8, stream);
    (void)hipMemsetAsync(tag1, 0, 2 * HH * 8, stream);

    embed_kernel<<<TT, 128, 0, stream>>>(inputs, emb, xsb);
    f32_to_bf16<<<1024, 256, 0, stream>>>(w_ih0, w0b, (long)4 * HH * EE / 4);
    f32_to_bf16<<<2048, 256, 0, stream>>>(w_out, wob, (long)VV * HH / 4);

    // pre0 = xs @ w_ih0^T + b_ih0 + b_hh0
    gemm_bf16_nt<<<dim3(4 * HH / 128, TT / 128), 256, 0, stream>>>(
        xsb, w0b, b_ih0, b_hh0, pre0, EE, 4 * HH);

    // fused pipelined 2-layer recurrence
    lstm_fused<<<256, 512, 0, stream>>>(
        w_hh0, pre0, w_ih1, w_hh1, b_ih1, b_hh1,
        hist0, tag1, y1b,
        out + (size_t)TT * VV, out + (size_t)TT * VV + 2 * HH);

    // logits = ys1 @ w_out^T + b_out  (into d_out, softmax in place after)
    gemm_bf16_nt<<<dim3(VV / 128, TT / 128), 256, 0, stream>>>(
        y1b, wob, b_out, nullptr, out, HH, VV);
    softmax_kernel<<<TT, 256, 0, stream>>>(out);
}

// Round 3
// 8305.088 us; speedup vs baseline: 1.4227x; 1.0105x over previous
//
#include <hip/hip_runtime.h>
#include <cstdint>
#include <cstddef>

#define TT 2048
#define VV 32000
#define EE 512
#define HH 1024
#define LBLK 128   // blocks per layer in lstm_fused

typedef __bf16 bf16x8 __attribute__((ext_vector_type(8)));
typedef float f32x4 __attribute__((ext_vector_type(4)));

static __device__ __forceinline__ unsigned short f2b(float f) {
    unsigned u = __float_as_uint(f);
    unsigned r = (u + 0x7fffu + ((u >> 16) & 1u)) >> 16;   // RNE
    return (unsigned short)r;
}
static __device__ __forceinline__ float b2f(unsigned bits16) {
    return __uint_as_float(bits16 << 16);
}

// ---------------- embedding gather -> bf16 ----------------
__global__ __launch_bounds__(128) void embed_kernel(
    const int* __restrict__ tok, const float* __restrict__ emb,
    unsigned short* __restrict__ xs_b) {
    int t = blockIdx.x;
    int e4 = threadIdx.x;
    const float4* src = (const float4*)(emb + (size_t)tok[t] * EE);
    float4 v = src[e4];
    ushort4 o;
    o.x = f2b(v.x); o.y = f2b(v.y); o.z = f2b(v.z); o.w = f2b(v.w);
    ((ushort4*)(xs_b + (size_t)t * EE))[e4] = o;
}

// ---------------- generic f32 -> bf16 ----------------
__global__ __launch_bounds__(256) void f32_to_bf16(
    const float* __restrict__ in, unsigned short* __restrict__ out, long n4) {
    long i = (long)blockIdx.x * blockDim.x + threadIdx.x;
    long stride = (long)gridDim.x * blockDim.x;
    for (; i < n4; i += stride) {
        float4 v = ((const float4*)in)[i];
        ushort4 o;
        o.x = f2b(v.x); o.y = f2b(v.y); o.z = f2b(v.z); o.w = f2b(v.w);
        ((ushort4*)out)[i] = o;
    }
}

// ---------------- bf16 MFMA GEMM: C[M,N] = A[M,K] * B[N,K]^T + bias ----------------
__global__ __launch_bounds__(256) void gemm_bf16_nt(
    const unsigned short* __restrict__ A,   // [M][K] bf16 bits
    const unsigned short* __restrict__ B,   // [N][K] bf16 bits
    const float* __restrict__ bias1,        // [N] or null
    const float* __restrict__ bias2,        // [N] or null
    float* __restrict__ C,                  // [M][N]
    int K, int N) {
    __shared__ unsigned short ldsA[128 * 64];
    __shared__ unsigned short ldsB[128 * 64];
    const int tid = threadIdx.x;
    const int l = tid & 63;
    const int w = tid >> 6;
    const int wm = (w >> 1) * 64;
    const int wn = (w & 1) * 64;
    const int bm = blockIdx.y, bn = blockIdx.x;
    const size_t a_base = (size_t)bm * 128 * K;
    const size_t b_base = (size_t)bn * 128 * K;
    const int srow = tid >> 3;
    const int skc = tid & 7;

    f32x4 acc[4][4];
    for (int i = 0; i < 4; ++i)
        for (int j = 0; j < 4; ++j)
            acc[i][j] = (f32x4){0.f, 0.f, 0.f, 0.f};

    for (int kt = 0; kt < K; kt += 64) {
        uint4 av[4], bv[4];
#pragma unroll
        for (int i = 0; i < 4; ++i) {
            int row = srow + i * 32;
            av[i] = ((const uint4*)(A + a_base + (size_t)row * K + kt))[skc];
            bv[i] = ((const uint4*)(B + b_base + (size_t)row * K + kt))[skc];
        }
        __syncthreads();
#pragma unroll
        for (int i = 0; i < 4; ++i) {
            int row = srow + i * 32;
            int off = row * 128 + ((skc * 16) ^ ((row & 7) << 4));
            *(uint4*)((char*)ldsA + off) = av[i];
            *(uint4*)((char*)ldsB + off) = bv[i];
        }
        __syncthreads();
#pragma unroll
        for (int ks = 0; ks < 2; ++ks) {
            bf16x8 af[4], bfr[4];
            int kb = ks * 64 + (l >> 4) * 16;
#pragma unroll
            for (int f = 0; f < 4; ++f) {
                int ar = wm + f * 16 + (l & 15);
                af[f] = *(const bf16x8*)((const char*)ldsA + ar * 128 + (kb ^ ((ar & 7) << 4)));
                int br = wn + f * 16 + (l & 15);
                bfr[f] = *(const bf16x8*)((const char*)ldsB + br * 128 + (kb ^ ((br & 7) << 4)));
            }
#pragma unroll
            for (int fm = 0; fm < 4; ++fm)
#pragma unroll
                for (int fn = 0; fn < 4; ++fn)
                    acc[fm][fn] = __builtin_amdgcn_mfma_f32_16x16x32_bf16(
                        af[fm], bfr[fn], acc[fm][fn], 0, 0, 0);
        }
    }
    const int r0 = (l >> 4) * 4, cn = (l & 15);
#pragma unroll
    for (int fm = 0; fm < 4; ++fm)
#pragma unroll
        for (int fn = 0; fn < 4; ++fn) {
            int col = bn * 128 + wn + fn * 16 + cn;
            float bb = (bias1 ? bias1[col] : 0.f) + (bias2 ? bias2[col] : 0.f);
#pragma unroll
            for (int r = 0; r < 4; ++r) {
                int rowg = bm * 128 + wm + fm * 16 + r0 + r;
                C[(size_t)rowg * N + col] = acc[fm][fn][r] + bb;
            }
        }
}

// ---------------- fused 2-layer pipelined LSTM recurrence ----------------
// 256 blocks x 512 threads. Blocks 0..127: layer 0; 128..255: layer 1.
// Each block owns 8 hidden units; wave wv owns unit j0+wv; W rows fp32 in regs.
// Comm: packed u32 {tag16 (hi), bf16 h (lo)}; each thread polls one u64 (2 entries).
// One __syncthreads per step per layer (parity-double-buffered LDS staging).
__global__ __launch_bounds__(512, 2) void lstm_fused(
    const float* __restrict__ Whh0,           // [4H][H]
    const float* __restrict__ pre0,           // [T][4H] (x-proj + biases, layer 0)
    const float* __restrict__ Wih1,           // [4H][H]
    const float* __restrict__ Whh1,           // [4H][H]
    const float* __restrict__ bih1,           // [4H]
    const float* __restrict__ bhh1,           // [4H]
    unsigned* __restrict__ hist0,             // [T][H] packed h0 history
    unsigned* __restrict__ tag1,              // [2][H] packed h1 double buffer
    unsigned short* __restrict__ y1b,         // [T][H] bf16 layer-1 output
    float* __restrict__ hfb,                  // out + T*V      (h stack [2][H])
    float* __restrict__ cfb) {                // out + T*V + 2H (c stack [2][H])
    const int tid  = threadIdx.x;
    const int wv   = tid >> 6;
    const int lane = tid & 63;
    const int e0   = tid * 2;            // staged entry pair

    __shared__ float hA[2][HH];
    __shared__ float hB[2][HH];

    if (blockIdx.x < LBLK) {
        // ================= layer 0 =================
        const int j = blockIdx.x * 8 + wv;
        float w[4][16];
#pragma unroll
        for (int g = 0; g < 4; ++g)
#pragma unroll
            for (int k = 0; k < 16; ++k)
                w[g][k] = Whh0[(size_t)(g * HH + j) * HH + lane + 64 * k];

        float c = 0.f;
        // prime px for t=0
        float px0 = pre0[0 * HH + j];
        float px1 = pre0[1 * HH + j];
        float px2 = pre0[2 * HH + j];
        float px3 = pre0[3 * HH + j];
        for (int t = 0; t < TT; ++t) {
            // issue next step's px loads first (a full round to cover HBM latency)
            float nx0 = 0.f, nx1 = 0.f, nx2 = 0.f, nx3 = 0.f;
            if (t + 1 < TT) {
                const float* p = pre0 + (size_t)(t + 1) * 4 * HH + j;
                nx0 = p[0 * HH]; nx1 = p[1 * HH]; nx2 = p[2 * HH]; nx3 = p[3 * HH];
            }
            const int par = t & 1;
            if (t > 0) {
                const unsigned long long* src =
                    (const unsigned long long*)(hist0 + (size_t)(t - 1) * HH);
                const unsigned want = (unsigned)t;
                unsigned long long v;
                while (true) {
                    v = __hip_atomic_load(src + tid, __ATOMIC_RELAXED, __HIP_MEMORY_SCOPE_AGENT);
                    if (((unsigned)(v >> 16) & 0xffffu) == want && (unsigned)(v >> 48) == want)
                        break;
                    __builtin_amdgcn_s_sleep(1);
                }
                hA[par][e0]     = b2f((unsigned)v & 0xffffu);
                hA[par][e0 + 1] = b2f((unsigned)(v >> 32) & 0xffffu);
            } else {
                hA[par][e0] = 0.f; hA[par][e0 + 1] = 0.f;
            }
            __syncthreads();
            float d0 = 0.f, d1 = 0.f, d2 = 0.f, d3 = 0.f;
#pragma unroll
            for (int k = 0; k < 16; ++k) {
                float hv = hA[par][lane + 64 * k];
                d0 += w[0][k] * hv; d1 += w[1][k] * hv;
                d2 += w[2][k] * hv; d3 += w[3][k] * hv;
            }
#pragma unroll
            for (int off = 32; off; off >>= 1) {
                d0 += __shfl_xor(d0, off); d1 += __shfl_xor(d1, off);
                d2 += __shfl_xor(d2, off); d3 += __shfl_xor(d3, off);
            }
            float gi = px0 + d0, gf = px1 + d1, gg = px2 + d2, go = px3 + d3;
            float i_ = 1.f / (1.f + __expf(-gi));
            float f_ = 1.f / (1.f + __expf(-gf));
            float eg = __expf(-2.f * gg); float g_ = (1.f - eg) / (1.f + eg);
            float o_ = 1.f / (1.f + __expf(-go));
            c = f_ * c + i_ * g_;
            float ec = __expf(-2.f * c); float tc = (1.f - ec) / (1.f + ec);
            float h = o_ * tc;
            if (lane == 0) {
                unsigned pack = ((unsigned)(t + 1) << 16) | (unsigned)f2b(h);
                __hip_atomic_store(hist0 + (size_t)t * HH + j, pack,
                                   __ATOMIC_RELAXED, __HIP_MEMORY_SCOPE_AGENT);
                if (t == TT - 1) { hfb[j] = h; cfb[j] = c; }
            }
            px0 = nx0; px1 = nx1; px2 = nx2; px3 = nx3;
        }
    } else {
        // ================= layer 1 (pipelined, 1 step behind) =================
        const int j = (blockIdx.x - LBLK) * 8 + wv;
        float wi[4][16], wh[4][16], bs[4];
#pragma unroll
        for (int g = 0; g < 4; ++g) {
#pragma unroll
            for (int k = 0; k < 16; ++k) {
                wi[g][k] = Wih1[(size_t)(g * HH + j) * HH + lane + 64 * k];
                wh[g][k] = Whh1[(size_t)(g * HH + j) * HH + lane + 64 * k];
            }
            bs[g] = bih1[g * HH + j] + bhh1[g * HH + j];
        }

        float c = 0.f;
        for (int t = 0; t < TT; ++t) {
            const int par = t & 1;
            // ---- combined poll: h0_t (tag t+1) and h1_{t-1} (tag t), max-semantics ----
            {
                const unsigned long long* srcA =
                    (const unsigned long long*)(hist0 + (size_t)t * HH);
                const unsigned long long* srcB =
                    (const unsigned long long*)(tag1 + (size_t)par * HH);
                const unsigned wantA = (unsigned)(t + 1);
                const unsigned wantB = (unsigned)t;
                unsigned long long vA = 0, vB = 0;
                bool rA = false, rB = (t == 0);
                while (true) {
                    if (!rA) {
                        vA = __hip_atomic_load(srcA + tid, __ATOMIC_RELAXED, __HIP_MEMORY_SCOPE_AGENT);
                        rA = ((unsigned)(vA >> 16) & 0xffffu) == wantA && (unsigned)(vA >> 48) == wantA;
                    }
                    if (!rB) {
                        vB = __hip_atomic_load(srcB + tid, __ATOMIC_RELAXED, __HIP_MEMORY_SCOPE_AGENT);
                        rB = ((unsigned)(vB >> 16) & 0xffffu) == wantB && (unsigned)(vB >> 48) == wantB;
                    }
                    if (rA & rB) break;
                    __builtin_amdgcn_s_sleep(1);
                }
                hA[par][e0]     = b2f((unsigned)vA & 0xffffu);
                hA[par][e0 + 1] = b2f((unsigned)(vA >> 32) & 0xffffu);
                if (t > 0) {
                    hB[par][e0]     = b2f((unsigned)vB & 0xffffu);
                    hB[par][e0 + 1] = b2f((unsigned)(vB >> 32) & 0xffffu);
                } else {
                    hB[par][e0] = 0.f; hB[par][e0 + 1] = 0.f;
                }
            }
            __syncthreads();
            float d0 = 0.f, d1 = 0.f, d2 = 0.f, d3 = 0.f;
#pragma unroll
            for (int k = 0; k < 16; ++k) {
                float ha = hA[par][lane + 64 * k];
                float hb = hB[par][lane + 64 * k];
                d0 += wi[0][k] * ha + wh[0][k] * hb;
                d1 += wi[1][k] * ha + wh[1][k] * hb;
                d2 += wi[2][k] * ha + wh[2][k] * hb;
                d3 += wi[3][k] * ha + wh[3][k] * hb;
            }
#pragma unroll
            for (int off = 32; off; off >>= 1) {
                d0 += __shfl_xor(d0, off); d1 += __shfl_xor(d1, off);
                d2 += __shfl_xor(d2, off); d3 += __shfl_xor(d3, off);
            }
            float gi = bs[0] + d0, gf = bs[1] + d1, gg = bs[2] + d2, go = bs[3] + d3;
            float i_ = 1.f / (1.f + __expf(-gi));
            float f_ = 1.f / (1.f + __expf(-gf));
            float eg = __expf(-2.f * gg); float g_ = (1.f - eg) / (1.f + eg);
            float o_ = 1.f / (1.f + __expf(-go));
            c = f_ * c + i_ * g_;
            float ec = __expf(-2.f * c); float tc = (1.f - ec) / (1.f + ec);
            float h = o_ * tc;
            if (lane == 0) {
                unsigned short hb16 = f2b(h);
                unsigned pack = ((unsigned)(t + 1) << 16) | (unsigned)hb16;
                __hip_atomic_store(tag1 + (size_t)((t + 1) & 1) * HH + j, pack,
                                   __ATOMIC_RELAXED, __HIP_MEMORY_SCOPE_AGENT);
                y1b[(size_t)t * HH + j] = hb16;
                if (t == TT - 1) { hfb[HH + j] = h; cfb[HH + j] = c; }
            }
        }
    }
}

// ---------------- row softmax over V=32000, in place ----------------
__global__ __launch_bounds__(256) void softmax_kernel(float* __restrict__ data) {
    const int row = blockIdx.x;
    const int tid = threadIdx.x;
    float* p = data + (size_t)row * VV;
    float m = -1e30f, s = 0.f;
    for (int i = tid * 4; i < VV; i += 1024) {
        float4 v = *(const float4*)(p + i);
        float x[4] = {v.x, v.y, v.z, v.w};
#pragma unroll
        for (int q = 0; q < 4; ++q) {
            float xv = x[q];
            if (xv > m) { s = s * __expf(m - xv) + 1.f; m = xv; }
            else s += __expf(xv - m);
        }
    }
#pragma unroll
    for (int off = 32; off; off >>= 1) {
        float mo = __shfl_xor(m, off);
        float so = __shfl_xor(s, off);
        float mn = fmaxf(m, mo);
        s = s * __expf(m - mn) + so * __expf(mo - mn);
        m = mn;
    }
    __shared__ float sm[4], ss[4];
    int wvv = tid >> 6;
    if ((tid & 63) == 0) { sm[wvv] = m; ss[wvv] = s; }
    __syncthreads();
    float M = fmaxf(fmaxf(sm[0], sm[1]), fmaxf(sm[2], sm[3]));
    float S = ss[0] * __expf(sm[0] - M) + ss[1] * __expf(sm[1] - M) +
              ss[2] * __expf(sm[2] - M) + ss[3] * __expf(sm[3] - M);
    float inv = 1.f / S;
    for (int i = tid * 4; i < VV; i += 1024) {
        float4 v = *(const float4*)(p + i);
        v.x = __expf(v.x - M) * inv;
        v.y = __expf(v.y - M) * inv;
        v.z = __expf(v.z - M) * inv;
        v.w = __expf(v.w - M) * inv;
        *(float4*)(p + i) = v;
    }
}

extern "C" void kernel_launch(void* const* d_in, const int* in_sizes, int n_in,
                              void* d_out, int out_size, void* d_ws, size_t ws_size,
                              hipStream_t stream) {
    const int*   inputs = (const int*)d_in[0];
    const float* emb    = (const float*)d_in[1];
    const float* w_ih0  = (const float*)d_in[2];
    const float* w_hh0  = (const float*)d_in[3];
    const float* b_ih0  = (const float*)d_in[4];
    const float* b_hh0  = (const float*)d_in[5];
    const float* w_ih1  = (const float*)d_in[6];
    const float* w_hh1  = (const float*)d_in[7];
    const float* b_ih1  = (const float*)d_in[8];
    const float* b_hh1  = (const float*)d_in[9];
    const float* w_out  = (const float*)d_in[10];
    const float* b_out  = (const float*)d_in[11];
    float* out = (float*)d_out;

    char* ws = (char*)d_ws;
    size_t off = 0;
    auto alloc = [&](size_t bytes) -> void* {
        void* p = ws + off;
        off += (bytes + 255) & ~(size_t)255;
        return p;
    };
    float* pre0          = (float*)alloc((size_t)TT * 4 * HH * 4);
    unsigned short* xsb  = (unsigned short*)alloc((size_t)TT * EE * 2);
    unsigned short* w0b  = (unsigned short*)alloc((size_t)4 * HH * EE * 2);
    unsigned short* wob  = (unsigned short*)alloc((size_t)VV * HH * 2);
    unsigned short* y1b  = (unsigned short*)alloc((size_t)TT * HH * 2);
    unsigned* hist0      = (unsigned*)alloc((size_t)TT * HH * 4);
    unsigned* tag1       = (unsigned*)alloc(2 * HH * 4);
    if (off > ws_size) return;

    (void)hipMemsetAsync(hist0, 0, (size_t)TT * HH * 4, stream);
    (void)hipMemsetAsync(tag1, 0, 2 * HH * 4, stream);

    embed_kernel<<<TT, 128, 0, stream>>>(inputs, emb, xsb);
    f32_to_bf16<<<1024, 256, 0, stream>>>(w_ih0, w0b, (long)4 * HH * EE / 4);
    f32_to_bf16<<<2048, 256, 0, stream>>>(w_out, wob, (long)VV * HH / 4);

    // pre0 = xs @ w_ih0^T + b_ih0 + b_hh0
    gemm_bf16_nt<<<dim3(4 * HH / 128, TT / 128), 256, 0, stream>>>(
        xsb, w0b, b_ih0, b_hh0, pre0, EE, 4 * HH);

    // fused pipelined 2-layer recurrence
    lstm_fused<<<256, 512, 0, stream>>>(
        w_hh0, pre0, w_ih1, w_hh1, b_ih1, b_hh1,
        hist0, tag1, y1b,
        out + (size_t)TT * VV, out + (size_t)TT * VV + 2 * HH);

    // logits = ys1 @ w_out^T + b_out  (into d_out, softmax in place after)
    gemm_bf16_nt<<<dim3(VV / 128, TT / 128), 256, 0, stream>>>(
        y1b, wob, b_out, nullptr, out, HH, VV);
    softmax_kernel<<<TT, 256, 0, stream>>>(out);
}